// Round 3
// baseline (390.993 us; speedup 1.0000x reference)
//
#include <hip/hip_runtime.h>

#define NUM_USERS 100000
#define NUM_ITEMS 50000
#define N_NODES   150000   // NUM_USERS + NUM_ITEMS
#define DIM       64
#define NNZ       1000000
#define BATCH     4096
#define N_LAYERS  3

#define SCAN_B 512
#define NBLK ((N_NODES + SCAN_B - 1) / SCAN_B)   // 293

typedef unsigned int uint32;
typedef unsigned short ushort16;

// bf16 helpers (RNE convert, cheap expand)
__device__ __forceinline__ ushort f2bf(float f) {
    uint32 u = __float_as_uint(f);
    u += 0x7FFFu + ((u >> 16) & 1u);
    return (ushort)(u >> 16);
}
__device__ __forceinline__ float bf2f(ushort u) {
    return __uint_as_float(((uint32)u) << 16);
}

// ---------------------------------------------------------------------------
// CSR build step 1: histogram of row degrees
// ---------------------------------------------------------------------------
__global__ void hist_kernel(const int* __restrict__ rows, int* __restrict__ cnt) {
    int stride = gridDim.x * blockDim.x;
    for (int e = blockIdx.x * blockDim.x + threadIdx.x; e < NNZ; e += stride)
        atomicAdd(&cnt[rows[e]], 1);
}

// ---------------------------------------------------------------------------
// CSR build step 2a: per-block scan (512/block); rowptr <- block-local
// exclusive scan, blksum <- block total.
// ---------------------------------------------------------------------------
__global__ __launch_bounds__(SCAN_B) void scan_block_kernel(
        const int* __restrict__ cnt, int* __restrict__ rowptr,
        int* __restrict__ blksum) {
    __shared__ int sh[SCAN_B];
    int i = blockIdx.x * SCAN_B + threadIdx.x;
    int v = (i < N_NODES) ? cnt[i] : 0;
    sh[threadIdx.x] = v;
    __syncthreads();
    for (int off = 1; off < SCAN_B; off <<= 1) {
        int t = (threadIdx.x >= off) ? sh[threadIdx.x - off] : 0;
        __syncthreads();
        sh[threadIdx.x] += t;
        __syncthreads();
    }
    if (i < N_NODES) rowptr[i] = sh[threadIdx.x] - v;
    if (threadIdx.x == SCAN_B - 1) blksum[blockIdx.x] = sh[SCAN_B - 1];
}

// ---------------------------------------------------------------------------
// CSR build step 2b: single-block exclusive scan of block sums
// ---------------------------------------------------------------------------
__global__ __launch_bounds__(SCAN_B) void scan_top_kernel(int* __restrict__ blksum) {
    __shared__ int sh[SCAN_B];
    int v = (threadIdx.x < NBLK) ? blksum[threadIdx.x] : 0;
    sh[threadIdx.x] = v;
    __syncthreads();
    for (int off = 1; off < SCAN_B; off <<= 1) {
        int t = (threadIdx.x >= off) ? sh[threadIdx.x - off] : 0;
        __syncthreads();
        sh[threadIdx.x] += t;
        __syncthreads();
    }
    if (threadIdx.x < NBLK) blksum[threadIdx.x] = sh[threadIdx.x] - v;
}

// ---------------------------------------------------------------------------
// CSR build step 2c: add block offsets; init cursor; rowptr[N]=NNZ
// ---------------------------------------------------------------------------
__global__ void scan_fix_kernel(int* __restrict__ rowptr,
                                const int* __restrict__ blksum,
                                int* __restrict__ cursor) {
    int i = blockIdx.x * blockDim.x + threadIdx.x;
    if (i < N_NODES) {
        int r = rowptr[i] + blksum[i / SCAN_B];
        rowptr[i] = r;
        cursor[i] = r;
    }
    if (i == 0) rowptr[N_NODES] = NNZ;
}

// ---------------------------------------------------------------------------
// CSR build step 3: scatter (col, val) packed as int2 into CSR slots
// ---------------------------------------------------------------------------
__global__ void scatter_kernel(const int* __restrict__ rows,
                               const int* __restrict__ cols,
                               const float* __restrict__ vals,
                               int* __restrict__ cursor,
                               int2* __restrict__ edges) {
    int stride = gridDim.x * blockDim.x;
    for (int e = blockIdx.x * blockDim.x + threadIdx.x; e < NNZ; e += stride) {
        int r = rows[e];
        int pos = atomicAdd(&cursor[r], 1);
        edges[pos] = make_int2(cols[e], __float_as_int(vals[e]));
    }
}

// ---------------------------------------------------------------------------
// convert: xb = bf16(concat(user_emb, item_emb)), vectorized
// ---------------------------------------------------------------------------
__global__ void convert_kernel(const float* __restrict__ user_emb,
                               const float* __restrict__ item_emb,
                               ushort* __restrict__ xb) {
    const int64_t total4 = (int64_t)N_NODES * DIM / 4;
    const int64_t user4  = (int64_t)NUM_USERS * DIM / 4;
    int64_t stride = (int64_t)gridDim.x * blockDim.x;
    for (int64_t i = (int64_t)blockIdx.x * blockDim.x + threadIdx.x;
         i < total4; i += stride) {
        float4 v = (i < user4) ? ((const float4*)user_emb)[i]
                               : ((const float4*)item_emb)[i - user4];
        ushort4 o;
        o.x = f2bf(v.x); o.y = f2bf(v.y); o.z = f2bf(v.z); o.w = f2bf(v.w);
        ((ushort4*)xb)[i] = o;
    }
}

// ---------------------------------------------------------------------------
// SpMM (CSR, bf16 features): one wave per 4 rows, lane = dim.
// 4 interleaved accumulators -> 4 independent gather chains in flight.
// ---------------------------------------------------------------------------
__global__ __launch_bounds__(256) void spmm4_kernel(
        const int* __restrict__ rowptr,
        const int2* __restrict__ edges,
        const ushort* __restrict__ xin,
        ushort* __restrict__ yout) {
    const int lane = threadIdx.x & 63;
    const int w = (int)(((uint32)blockIdx.x * blockDim.x + threadIdx.x) >> 6);
    const int r0 = w * 4;
    if (r0 >= N_NODES) return;

    int4 rp = *(const int4*)&rowptr[r0];
    int  rp4 = rowptr[r0 + 4];
    int e[4]   = {rp.x, rp.y, rp.z, rp.w};
    int end[4] = {rp.y, rp.z, rp.w, rp4};
    float acc[4] = {0.f, 0.f, 0.f, 0.f};

    for (;;) {
        int2 ed[4];
        bool act[4];
        bool any = false;
        #pragma unroll
        for (int j = 0; j < 4; ++j) {
            act[j] = (e[j] < end[j]);
            if (act[j]) { ed[j] = edges[e[j]]; any = true; }
        }
        if (!any) break;
        #pragma unroll
        for (int j = 0; j < 4; ++j) {
            if (act[j]) {
                float xv = bf2f(xin[(int64_t)ed[j].x * DIM + lane]);
                acc[j] = fmaf(__int_as_float(ed[j].y), xv, acc[j]);
                e[j]++;
            }
        }
    }
    #pragma unroll
    for (int j = 0; j < 4; ++j)
        yout[(int64_t)(r0 + j) * DIM + lane] = f2bf(acc[j]);
}

// ---------------------------------------------------------------------------
// Per-batch accumulator update: acc[i] (+)= x[row(i)]
// FIRST reads fp32 embedding tables; else reads bf16 propagated features.
// ---------------------------------------------------------------------------
template <bool FIRST>
__global__ void gather_acc_kernel(const int* __restrict__ user_idx,
                                  const int* __restrict__ item_idx,
                                  const ushort* __restrict__ x,
                                  const float* __restrict__ user_emb,
                                  const float* __restrict__ item_emb,
                                  float* __restrict__ acc) {
    const int lane = threadIdx.x & 63;
    const int i = (int)(((uint32)blockIdx.x * blockDim.x + threadIdx.x) >> 6);
    if (i >= 2 * BATCH) return;
    if (FIRST) {
        float v;
        if (i < BATCH) v = user_emb[(int64_t)user_idx[i] * DIM + lane];
        else           v = item_emb[(int64_t)item_idx[i - BATCH] * DIM + lane];
        acc[(int64_t)i * DIM + lane] = v;
    } else {
        int row = (i < BATCH) ? user_idx[i] : (NUM_USERS + item_idx[i - BATCH]);
        acc[(int64_t)i * DIM + lane] += bf2f(x[(int64_t)row * DIM + lane]);
    }
}

// ---------------------------------------------------------------------------
// Output: rating dot + scaled user/item embeddings
// ---------------------------------------------------------------------------
__global__ void out_kernel(const float* __restrict__ acc, float* __restrict__ out) {
    const int lane = threadIdx.x & 63;
    const int b = (int)(((uint32)blockIdx.x * blockDim.x + threadIdx.x) >> 6);
    if (b >= BATCH) return;
    float uv = acc[(int64_t)b * DIM + lane] * 0.25f;
    float iv = acc[(int64_t)(BATCH + b) * DIM + lane] * 0.25f;
    out[(int64_t)BATCH + (int64_t)b * DIM + lane] = uv;
    out[(int64_t)BATCH + (int64_t)BATCH * DIM + (int64_t)b * DIM + lane] = iv;
    float p = uv * iv;
    #pragma unroll
    for (int off = 32; off >= 1; off >>= 1) p += __shfl_down(p, off, 64);
    if (lane == 0) out[b] = p;
}

// ---------------------------------------------------------------------------
extern "C" void kernel_launch(void* const* d_in, const int* in_sizes, int n_in,
                              void* d_out, int out_size, void* d_ws, size_t ws_size,
                              hipStream_t stream) {
    const int*   user_idx = (const int*)  d_in[0];
    const int*   item_idx = (const int*)  d_in[1];
    const int*   rows     = (const int*)  d_in[2];
    const int*   cols     = (const int*)  d_in[3];
    const float* vals     = (const float*)d_in[4];
    const float* user_emb = (const float*)d_in[5];
    const float* item_emb = (const float*)d_in[6];
    float*       out      = (float*)d_out;

    // ---- workspace layout ----
    char* base = (char*)d_ws;
    size_t off = 0;
    auto alloc = [&](size_t bytes) -> char* {
        char* p = base + off;
        off = (off + bytes + 255) & ~(size_t)255;
        return p;
    };
    int*    cnt    = (int*)   alloc((size_t)(N_NODES + 1) * sizeof(int));
    int*    rowptr = (int*)   alloc((size_t)(N_NODES + 1) * sizeof(int));
    int*    cursor = (int*)   alloc((size_t)N_NODES * sizeof(int));
    int*    blksum = (int*)   alloc((size_t)NBLK * sizeof(int));
    int2*   edges  = (int2*)  alloc((size_t)NNZ * sizeof(int2));
    ushort* xb     = (ushort*)alloc((size_t)N_NODES * DIM * sizeof(ushort));
    ushort* buf0   = (ushort*)alloc((size_t)N_NODES * DIM * sizeof(ushort));
    ushort* buf1   = (ushort*)alloc((size_t)N_NODES * DIM * sizeof(ushort));
    float*  acc    = (float*) alloc((size_t)2 * BATCH * DIM * sizeof(float));

    const int TB = 256;

    // ---- CSR build ----
    hipMemsetAsync(cnt, 0, (size_t)(N_NODES + 1) * sizeof(int), stream);
    hist_kernel<<<2048, TB, 0, stream>>>(rows, cnt);
    scan_block_kernel<<<NBLK, SCAN_B, 0, stream>>>(cnt, rowptr, blksum);
    scan_top_kernel<<<1, SCAN_B, 0, stream>>>(blksum);
    scan_fix_kernel<<<(N_NODES + TB - 1) / TB, TB, 0, stream>>>(rowptr, blksum, cursor);
    scatter_kernel<<<2048, TB, 0, stream>>>(rows, cols, vals, cursor, edges);

    // ---- bf16 node features ----
    convert_kernel<<<2048, TB, 0, stream>>>(user_emb, item_emb, xb);

    // ---- propagation ----
    const int spmmBlocks = (N_NODES / 4 * 64 + TB - 1) / TB;   // 4 rows per wave
    const int gathBlocks = (2 * BATCH * 64 + TB - 1) / TB;

    gather_acc_kernel<true><<<gathBlocks, TB, 0, stream>>>(
        user_idx, item_idx, nullptr, user_emb, item_emb, acc);

    spmm4_kernel<<<spmmBlocks, TB, 0, stream>>>(rowptr, edges, xb, buf0);
    gather_acc_kernel<false><<<gathBlocks, TB, 0, stream>>>(
        user_idx, item_idx, buf0, nullptr, nullptr, acc);

    spmm4_kernel<<<spmmBlocks, TB, 0, stream>>>(rowptr, edges, buf0, buf1);
    gather_acc_kernel<false><<<gathBlocks, TB, 0, stream>>>(
        user_idx, item_idx, buf1, nullptr, nullptr, acc);

    spmm4_kernel<<<spmmBlocks, TB, 0, stream>>>(rowptr, edges, buf1, buf0);
    gather_acc_kernel<false><<<gathBlocks, TB, 0, stream>>>(
        user_idx, item_idx, buf0, nullptr, nullptr, acc);

    // ---- output ----
    out_kernel<<<(BATCH * 64 + TB - 1) / TB, TB, 0, stream>>>(acc, out);
}

// Round 4
// 247.985 us; speedup vs baseline: 1.5767x; 1.5767x over previous
//
#include <hip/hip_runtime.h>

#define NUM_USERS 100000
#define NUM_ITEMS 50000
#define N_NODES   150000   // NUM_USERS + NUM_ITEMS
#define DIM       64
#define NNZ       1000000
#define BATCH     4096
#define N_LAYERS  3

#define SCAN_B 512
#define NBLK ((N_NODES + SCAN_B - 1) / SCAN_B)   // 293

typedef unsigned int uint32;

// bf16 helpers (RNE convert, cheap expand)
__device__ __forceinline__ ushort f2bf(float f) {
    uint32 u = __float_as_uint(f);
    u += 0x7FFFu + ((u >> 16) & 1u);
    return (ushort)(u >> 16);
}
__device__ __forceinline__ float bf2f(ushort u) {
    return __uint_as_float(((uint32)u) << 16);
}

// ---------------------------------------------------------------------------
// CSR build step 1: histogram of row degrees
// ---------------------------------------------------------------------------
__global__ void hist_kernel(const int* __restrict__ rows, int* __restrict__ cnt) {
    int stride = gridDim.x * blockDim.x;
    for (int e = blockIdx.x * blockDim.x + threadIdx.x; e < NNZ; e += stride)
        atomicAdd(&cnt[rows[e]], 1);
}

// ---------------------------------------------------------------------------
// CSR build step 2a: per-block scan (512/block); rowptr <- block-local
// exclusive scan, blksum <- block total.
// ---------------------------------------------------------------------------
__global__ __launch_bounds__(SCAN_B) void scan_block_kernel(
        const int* __restrict__ cnt, int* __restrict__ rowptr,
        int* __restrict__ blksum) {
    __shared__ int sh[SCAN_B];
    int i = blockIdx.x * SCAN_B + threadIdx.x;
    int v = (i < N_NODES) ? cnt[i] : 0;
    sh[threadIdx.x] = v;
    __syncthreads();
    for (int off = 1; off < SCAN_B; off <<= 1) {
        int t = (threadIdx.x >= off) ? sh[threadIdx.x - off] : 0;
        __syncthreads();
        sh[threadIdx.x] += t;
        __syncthreads();
    }
    if (i < N_NODES) rowptr[i] = sh[threadIdx.x] - v;
    if (threadIdx.x == SCAN_B - 1) blksum[blockIdx.x] = sh[SCAN_B - 1];
}

// ---------------------------------------------------------------------------
// CSR build step 2b: single-block exclusive scan of block sums
// ---------------------------------------------------------------------------
__global__ __launch_bounds__(SCAN_B) void scan_top_kernel(int* __restrict__ blksum) {
    __shared__ int sh[SCAN_B];
    int v = (threadIdx.x < NBLK) ? blksum[threadIdx.x] : 0;
    sh[threadIdx.x] = v;
    __syncthreads();
    for (int off = 1; off < SCAN_B; off <<= 1) {
        int t = (threadIdx.x >= off) ? sh[threadIdx.x - off] : 0;
        __syncthreads();
        sh[threadIdx.x] += t;
        __syncthreads();
    }
    if (threadIdx.x < NBLK) blksum[threadIdx.x] = sh[threadIdx.x] - v;
}

// ---------------------------------------------------------------------------
// CSR build step 2c: add block offsets; init cursor; rowptr[N]=NNZ
// ---------------------------------------------------------------------------
__global__ void scan_fix_kernel(int* __restrict__ rowptr,
                                const int* __restrict__ blksum,
                                int* __restrict__ cursor) {
    int i = blockIdx.x * blockDim.x + threadIdx.x;
    if (i < N_NODES) {
        int r = rowptr[i] + blksum[i / SCAN_B];
        rowptr[i] = r;
        cursor[i] = r;
    }
    if (i == 0) rowptr[N_NODES] = NNZ;
}

// ---------------------------------------------------------------------------
// CSR build step 3: XCD-sliced scatter. Block blockIdx&7 handles rows in
// slice [s*18750, (s+1)*18750) only -> each XCD's writes live in a 1MB
// region that fits its private L2, so 64B lines fill before writeback.
// ---------------------------------------------------------------------------
__global__ __launch_bounds__(256) void scatter_kernel(
        const int* __restrict__ rows,
        const int* __restrict__ cols,
        const float* __restrict__ vals,
        int* __restrict__ cursor,
        int2* __restrict__ edges) {
    const int slice  = blockIdx.x & 7;              // presumed XCD (round-robin)
    const int rowLo  = slice * (N_NODES / 8);       // 18750 rows per slice
    const int rowHi  = rowLo + (N_NODES / 8);
    int tid    = (int)((blockIdx.x >> 3) * blockDim.x + threadIdx.x);
    int stride = (int)((gridDim.x >> 3) * blockDim.x);
    for (int e = tid; e < NNZ; e += stride) {
        int r = rows[e];
        if (r >= rowLo && r < rowHi) {
            int pos = atomicAdd(&cursor[r], 1);
            edges[pos] = make_int2(cols[e], __float_as_int(vals[e]));
        }
    }
}

// ---------------------------------------------------------------------------
// convert: xb = bf16(concat(user_emb, item_emb)), vectorized
// ---------------------------------------------------------------------------
__global__ void convert_kernel(const float* __restrict__ user_emb,
                               const float* __restrict__ item_emb,
                               ushort* __restrict__ xb) {
    const int64_t total4 = (int64_t)N_NODES * DIM / 4;
    const int64_t user4  = (int64_t)NUM_USERS * DIM / 4;
    int64_t stride = (int64_t)gridDim.x * blockDim.x;
    for (int64_t i = (int64_t)blockIdx.x * blockDim.x + threadIdx.x;
         i < total4; i += stride) {
        float4 v = (i < user4) ? ((const float4*)user_emb)[i]
                               : ((const float4*)item_emb)[i - user4];
        ushort4 o;
        o.x = f2bf(v.x); o.y = f2bf(v.y); o.z = f2bf(v.z); o.w = f2bf(v.w);
        ((ushort4*)xb)[i] = o;
    }
}

// ---------------------------------------------------------------------------
// SpMM (CSR, bf16): one wave per 8 rows, lane = dim. BRANCH-FREE chains:
// uniform trip count (max degree in the wave's 8 rows); inactive chains
// load edges[0] (hot line) with value cndmask'd to 0. Edge indices are
// readfirstlane'd so edge loads use the scalar path and gather addresses
// are SGPR-base + lane. 8 independent gathers in flight per wave.
// ---------------------------------------------------------------------------
__global__ __launch_bounds__(256) void spmm8_kernel(
        const int* __restrict__ rowptr,
        const int2* __restrict__ edges,
        const ushort* __restrict__ xin,
        ushort* __restrict__ yout) {
    const int lane = threadIdx.x & 63;
    const int w = (int)(((uint32)blockIdx.x * blockDim.x + threadIdx.x) >> 6);
    const int r0 = w * 8;
    if (r0 >= N_NODES) return;

    int rp[9];
    #pragma unroll
    for (int j = 0; j < 9; ++j) rp[j] = rowptr[r0 + j];

    int e[8], end[8];
    int trips = 0;
    #pragma unroll
    for (int j = 0; j < 8; ++j) {
        e[j] = rp[j]; end[j] = rp[j + 1];
        trips = max(trips, end[j] - e[j]);
    }
    float acc[8] = {0.f, 0.f, 0.f, 0.f, 0.f, 0.f, 0.f, 0.f};

    for (int t = 0; t < trips; ++t) {
        int   col[8];
        float val[8];
        #pragma unroll
        for (int j = 0; j < 8; ++j) {
            bool act = e[j] < end[j];
            int idx  = __builtin_amdgcn_readfirstlane(act ? e[j] : 0);
            int2 ed  = edges[idx];
            col[j] = __builtin_amdgcn_readfirstlane(ed.x);
            val[j] = act ? __int_as_float(ed.y) : 0.f;
            e[j]  += act ? 1 : 0;
        }
        #pragma unroll
        for (int j = 0; j < 8; ++j) {
            float xv = bf2f(xin[(int64_t)col[j] * DIM + lane]);
            acc[j] = fmaf(val[j], xv, acc[j]);
        }
    }
    #pragma unroll
    for (int j = 0; j < 8; ++j)
        yout[(int64_t)(r0 + j) * DIM + lane] = f2bf(acc[j]);
}

// ---------------------------------------------------------------------------
// Per-batch accumulator update: acc[i] (+)= x[row(i)]
// FIRST reads fp32 embedding tables; else reads bf16 propagated features.
// ---------------------------------------------------------------------------
template <bool FIRST>
__global__ void gather_acc_kernel(const int* __restrict__ user_idx,
                                  const int* __restrict__ item_idx,
                                  const ushort* __restrict__ x,
                                  const float* __restrict__ user_emb,
                                  const float* __restrict__ item_emb,
                                  float* __restrict__ acc) {
    const int lane = threadIdx.x & 63;
    const int i = (int)(((uint32)blockIdx.x * blockDim.x + threadIdx.x) >> 6);
    if (i >= 2 * BATCH) return;
    if (FIRST) {
        float v;
        if (i < BATCH) v = user_emb[(int64_t)user_idx[i] * DIM + lane];
        else           v = item_emb[(int64_t)item_idx[i - BATCH] * DIM + lane];
        acc[(int64_t)i * DIM + lane] = v;
    } else {
        int row = (i < BATCH) ? user_idx[i] : (NUM_USERS + item_idx[i - BATCH]);
        acc[(int64_t)i * DIM + lane] += bf2f(x[(int64_t)row * DIM + lane]);
    }
}

// ---------------------------------------------------------------------------
// Output: rating dot + scaled user/item embeddings
// ---------------------------------------------------------------------------
__global__ void out_kernel(const float* __restrict__ acc, float* __restrict__ out) {
    const int lane = threadIdx.x & 63;
    const int b = (int)(((uint32)blockIdx.x * blockDim.x + threadIdx.x) >> 6);
    if (b >= BATCH) return;
    float uv = acc[(int64_t)b * DIM + lane] * 0.25f;
    float iv = acc[(int64_t)(BATCH + b) * DIM + lane] * 0.25f;
    out[(int64_t)BATCH + (int64_t)b * DIM + lane] = uv;
    out[(int64_t)BATCH + (int64_t)BATCH * DIM + (int64_t)b * DIM + lane] = iv;
    float p = uv * iv;
    #pragma unroll
    for (int off = 32; off >= 1; off >>= 1) p += __shfl_down(p, off, 64);
    if (lane == 0) out[b] = p;
}

// ---------------------------------------------------------------------------
extern "C" void kernel_launch(void* const* d_in, const int* in_sizes, int n_in,
                              void* d_out, int out_size, void* d_ws, size_t ws_size,
                              hipStream_t stream) {
    const int*   user_idx = (const int*)  d_in[0];
    const int*   item_idx = (const int*)  d_in[1];
    const int*   rows     = (const int*)  d_in[2];
    const int*   cols     = (const int*)  d_in[3];
    const float* vals     = (const float*)d_in[4];
    const float* user_emb = (const float*)d_in[5];
    const float* item_emb = (const float*)d_in[6];
    float*       out      = (float*)d_out;

    // ---- workspace layout ----
    char* base = (char*)d_ws;
    size_t off = 0;
    auto alloc = [&](size_t bytes) -> char* {
        char* p = base + off;
        off = (off + bytes + 255) & ~(size_t)255;
        return p;
    };
    int*    cnt    = (int*)   alloc((size_t)(N_NODES + 1) * sizeof(int));
    int*    rowptr = (int*)   alloc((size_t)(N_NODES + 1) * sizeof(int));
    int*    cursor = (int*)   alloc((size_t)N_NODES * sizeof(int));
    int*    blksum = (int*)   alloc((size_t)NBLK * sizeof(int));
    int2*   edges  = (int2*)  alloc((size_t)NNZ * sizeof(int2));
    ushort* xb     = (ushort*)alloc((size_t)N_NODES * DIM * sizeof(ushort));
    ushort* buf0   = (ushort*)alloc((size_t)N_NODES * DIM * sizeof(ushort));
    ushort* buf1   = (ushort*)alloc((size_t)N_NODES * DIM * sizeof(ushort));
    float*  acc    = (float*) alloc((size_t)2 * BATCH * DIM * sizeof(float));

    const int TB = 256;

    // ---- CSR build ----
    hipMemsetAsync(cnt, 0, (size_t)(N_NODES + 1) * sizeof(int), stream);
    hist_kernel<<<2048, TB, 0, stream>>>(rows, cnt);
    scan_block_kernel<<<NBLK, SCAN_B, 0, stream>>>(cnt, rowptr, blksum);
    scan_top_kernel<<<1, SCAN_B, 0, stream>>>(blksum);
    scan_fix_kernel<<<(N_NODES + TB - 1) / TB, TB, 0, stream>>>(rowptr, blksum, cursor);
    scatter_kernel<<<2048, TB, 0, stream>>>(rows, cols, vals, cursor, edges);

    // ---- bf16 node features ----
    convert_kernel<<<2048, TB, 0, stream>>>(user_emb, item_emb, xb);

    // ---- propagation ----
    const int spmmBlocks = (N_NODES / 8 * 64 + TB - 1) / TB;   // 8 rows per wave
    const int gathBlocks = (2 * BATCH * 64 + TB - 1) / TB;

    gather_acc_kernel<true><<<gathBlocks, TB, 0, stream>>>(
        user_idx, item_idx, nullptr, user_emb, item_emb, acc);

    spmm8_kernel<<<spmmBlocks, TB, 0, stream>>>(rowptr, edges, xb, buf0);
    gather_acc_kernel<false><<<gathBlocks, TB, 0, stream>>>(
        user_idx, item_idx, buf0, nullptr, nullptr, acc);

    spmm8_kernel<<<spmmBlocks, TB, 0, stream>>>(rowptr, edges, buf0, buf1);
    gather_acc_kernel<false><<<gathBlocks, TB, 0, stream>>>(
        user_idx, item_idx, buf1, nullptr, nullptr, acc);

    spmm8_kernel<<<spmmBlocks, TB, 0, stream>>>(rowptr, edges, buf1, buf0);
    gather_acc_kernel<false><<<gathBlocks, TB, 0, stream>>>(
        user_idx, item_idx, buf0, nullptr, nullptr, acc);

    // ---- output ----
    out_kernel<<<(BATCH * 64 + TB - 1) / TB, TB, 0, stream>>>(acc, out);
}

// Round 5
// 224.463 us; speedup vs baseline: 1.7419x; 1.1048x over previous
//
#include <hip/hip_runtime.h>

#define NUM_USERS 100000
#define NUM_ITEMS 50000
#define N_NODES   150000   // NUM_USERS + NUM_ITEMS
#define DIM       64
#define NNZ       1000000
#define BATCH     4096
#define N_LAYERS  3

#define SCAN_B 512
#define NBLK ((N_NODES + SCAN_B - 1) / SCAN_B)   // 293

typedef unsigned int uint32;

// bf16 helpers (RNE convert, cheap expand)
__device__ __forceinline__ ushort f2bf(float f) {
    uint32 u = __float_as_uint(f);
    u += 0x7FFFu + ((u >> 16) & 1u);
    return (ushort)(u >> 16);
}
__device__ __forceinline__ float bf2f(ushort u) {
    return __uint_as_float(((uint32)u) << 16);
}

// ---------------------------------------------------------------------------
// CSR build step 1: histogram of row degrees
// ---------------------------------------------------------------------------
__global__ void hist_kernel(const int* __restrict__ rows, int* __restrict__ cnt) {
    int stride = gridDim.x * blockDim.x;
    for (int e = blockIdx.x * blockDim.x + threadIdx.x; e < NNZ; e += stride)
        atomicAdd(&cnt[__builtin_nontemporal_load(&rows[e])], 1);
}

// ---------------------------------------------------------------------------
// CSR build step 2a: per-block scan (512/block)
// ---------------------------------------------------------------------------
__global__ __launch_bounds__(SCAN_B) void scan_block_kernel(
        const int* __restrict__ cnt, int* __restrict__ rowptr,
        int* __restrict__ blksum) {
    __shared__ int sh[SCAN_B];
    int i = blockIdx.x * SCAN_B + threadIdx.x;
    int v = (i < N_NODES) ? cnt[i] : 0;
    sh[threadIdx.x] = v;
    __syncthreads();
    for (int off = 1; off < SCAN_B; off <<= 1) {
        int t = (threadIdx.x >= off) ? sh[threadIdx.x - off] : 0;
        __syncthreads();
        sh[threadIdx.x] += t;
        __syncthreads();
    }
    if (i < N_NODES) rowptr[i] = sh[threadIdx.x] - v;
    if (threadIdx.x == SCAN_B - 1) blksum[blockIdx.x] = sh[SCAN_B - 1];
}

// ---------------------------------------------------------------------------
// CSR build step 2b: single-block exclusive scan of block sums
// ---------------------------------------------------------------------------
__global__ __launch_bounds__(SCAN_B) void scan_top_kernel(int* __restrict__ blksum) {
    __shared__ int sh[SCAN_B];
    int v = (threadIdx.x < NBLK) ? blksum[threadIdx.x] : 0;
    sh[threadIdx.x] = v;
    __syncthreads();
    for (int off = 1; off < SCAN_B; off <<= 1) {
        int t = (threadIdx.x >= off) ? sh[threadIdx.x - off] : 0;
        __syncthreads();
        sh[threadIdx.x] += t;
        __syncthreads();
    }
    if (threadIdx.x < NBLK) blksum[threadIdx.x] = sh[threadIdx.x] - v;
}

// ---------------------------------------------------------------------------
// CSR build step 2c: add block offsets; init cursor; rowptr[N]=NNZ
// ---------------------------------------------------------------------------
__global__ void scan_fix_kernel(int* __restrict__ rowptr,
                                const int* __restrict__ blksum,
                                int* __restrict__ cursor) {
    int i = blockIdx.x * blockDim.x + threadIdx.x;
    if (i < N_NODES) {
        int r = rowptr[i] + blksum[i / SCAN_B];
        rowptr[i] = r;
        cursor[i] = r;
    }
    if (i == 0) rowptr[N_NODES] = NNZ;
}

// ---------------------------------------------------------------------------
// CSR build step 3: XCD-sliced scatter. Block blockIdx&7 handles rows in
// slice [s*18750, (s+1)*18750) -> writes live in a 1MB region per XCD L2.
// Streaming reads are NONTEMPORAL so they don't evict dirty edge lines.
// ---------------------------------------------------------------------------
__global__ __launch_bounds__(256) void scatter_kernel(
        const int* __restrict__ rows,
        const int* __restrict__ cols,
        const float* __restrict__ vals,
        int* __restrict__ cursor,
        int2* __restrict__ edges) {
    const int slice  = blockIdx.x & 7;              // presumed XCD (round-robin)
    const int rowLo  = slice * (N_NODES / 8);
    const int rowHi  = rowLo + (N_NODES / 8);
    int tid    = (int)((blockIdx.x >> 3) * blockDim.x + threadIdx.x);
    int stride = (int)((gridDim.x >> 3) * blockDim.x);
    for (int e = tid; e < NNZ; e += stride) {
        int r = __builtin_nontemporal_load(&rows[e]);
        if (r >= rowLo && r < rowHi) {
            int c = __builtin_nontemporal_load(&cols[e]);
            float v = __builtin_nontemporal_load(&vals[e]);
            int pos = atomicAdd(&cursor[r], 1);
            edges[pos] = make_int2(c, __float_as_int(v));
        }
    }
}

// ---------------------------------------------------------------------------
// convert: xb = bf16(concat(user_emb, item_emb)), vectorized
// ---------------------------------------------------------------------------
__global__ void convert_kernel(const float* __restrict__ user_emb,
                               const float* __restrict__ item_emb,
                               ushort* __restrict__ xb) {
    const int64_t total4 = (int64_t)N_NODES * DIM / 4;
    const int64_t user4  = (int64_t)NUM_USERS * DIM / 4;
    int64_t stride = (int64_t)gridDim.x * blockDim.x;
    for (int64_t i = (int64_t)blockIdx.x * blockDim.x + threadIdx.x;
         i < total4; i += stride) {
        float4 v = (i < user4) ? ((const float4*)user_emb)[i]
                               : ((const float4*)item_emb)[i - user4];
        ushort4 o;
        o.x = f2bf(v.x); o.y = f2bf(v.y); o.z = f2bf(v.z); o.w = f2bf(v.w);
        ((ushort4*)xb)[i] = o;
    }
}

// ---------------------------------------------------------------------------
// SpMM (CSR, bf16): one wave per 8 rows, lane = dim, branch-free chains.
// ---------------------------------------------------------------------------
__global__ __launch_bounds__(256) void spmm8_kernel(
        const int* __restrict__ rowptr,
        const int2* __restrict__ edges,
        const ushort* __restrict__ xin,
        ushort* __restrict__ yout) {
    const int lane = threadIdx.x & 63;
    const int w = (int)(((uint32)blockIdx.x * blockDim.x + threadIdx.x) >> 6);
    const int r0 = w * 8;
    if (r0 >= N_NODES) return;

    int rp[9];
    #pragma unroll
    for (int j = 0; j < 9; ++j) rp[j] = rowptr[r0 + j];

    int e[8], end[8];
    int trips = 0;
    #pragma unroll
    for (int j = 0; j < 8; ++j) {
        e[j] = rp[j]; end[j] = rp[j + 1];
        trips = max(trips, end[j] - e[j]);
    }
    float acc[8] = {0.f, 0.f, 0.f, 0.f, 0.f, 0.f, 0.f, 0.f};

    for (int t = 0; t < trips; ++t) {
        int   col[8];
        float val[8];
        #pragma unroll
        for (int j = 0; j < 8; ++j) {
            bool act = e[j] < end[j];
            int idx  = __builtin_amdgcn_readfirstlane(act ? e[j] : 0);
            int2 ed  = edges[idx];
            col[j] = __builtin_amdgcn_readfirstlane(ed.x);
            val[j] = act ? __int_as_float(ed.y) : 0.f;
            e[j]  += act ? 1 : 0;
        }
        #pragma unroll
        for (int j = 0; j < 8; ++j) {
            float xv = bf2f(xin[(int64_t)col[j] * DIM + lane]);
            acc[j] = fmaf(val[j], xv, acc[j]);
        }
    }
    #pragma unroll
    for (int j = 0; j < 8; ++j)
        yout[(int64_t)(r0 + j) * DIM + lane] = f2bf(acc[j]);
}

// ---------------------------------------------------------------------------
// Layer-3 SpMM restricted to the 8192 batch rows, fused with acc update:
// acc[i] += sum_e val_e * x[col_e].  Same branch-free 8-chain structure.
// ---------------------------------------------------------------------------
__global__ __launch_bounds__(256) void spmm_batch_kernel(
        const int* __restrict__ user_idx,
        const int* __restrict__ item_idx,
        const int* __restrict__ rowptr,
        const int2* __restrict__ edges,
        const ushort* __restrict__ xin,
        float* __restrict__ acc) {
    const int lane = threadIdx.x & 63;
    const int w = (int)(((uint32)blockIdx.x * blockDim.x + threadIdx.x) >> 6);
    const int i0 = w * 8;
    if (i0 >= 2 * BATCH) return;

    int e[8], end[8];
    int trips = 0;
    #pragma unroll
    for (int j = 0; j < 8; ++j) {
        int i = i0 + j;
        int row = (i < BATCH) ? user_idx[i] : (NUM_USERS + item_idx[i - BATCH]);
        e[j]   = rowptr[row];
        end[j] = rowptr[row + 1];
        trips = max(trips, end[j] - e[j]);
    }
    float a[8] = {0.f, 0.f, 0.f, 0.f, 0.f, 0.f, 0.f, 0.f};

    for (int t = 0; t < trips; ++t) {
        int   col[8];
        float val[8];
        #pragma unroll
        for (int j = 0; j < 8; ++j) {
            bool act = e[j] < end[j];
            int idx  = __builtin_amdgcn_readfirstlane(act ? e[j] : 0);
            int2 ed  = edges[idx];
            col[j] = __builtin_amdgcn_readfirstlane(ed.x);
            val[j] = act ? __int_as_float(ed.y) : 0.f;
            e[j]  += act ? 1 : 0;
        }
        #pragma unroll
        for (int j = 0; j < 8; ++j) {
            float xv = bf2f(xin[(int64_t)col[j] * DIM + lane]);
            a[j] = fmaf(val[j], xv, a[j]);
        }
    }
    #pragma unroll
    for (int j = 0; j < 8; ++j)
        acc[(int64_t)(i0 + j) * DIM + lane] += a[j];
}

// ---------------------------------------------------------------------------
// Per-batch accumulator update: acc[i] (+)= x[row(i)]
// ---------------------------------------------------------------------------
template <bool FIRST>
__global__ void gather_acc_kernel(const int* __restrict__ user_idx,
                                  const int* __restrict__ item_idx,
                                  const ushort* __restrict__ x,
                                  const float* __restrict__ user_emb,
                                  const float* __restrict__ item_emb,
                                  float* __restrict__ acc) {
    const int lane = threadIdx.x & 63;
    const int i = (int)(((uint32)blockIdx.x * blockDim.x + threadIdx.x) >> 6);
    if (i >= 2 * BATCH) return;
    if (FIRST) {
        float v;
        if (i < BATCH) v = user_emb[(int64_t)user_idx[i] * DIM + lane];
        else           v = item_emb[(int64_t)item_idx[i - BATCH] * DIM + lane];
        acc[(int64_t)i * DIM + lane] = v;
    } else {
        int row = (i < BATCH) ? user_idx[i] : (NUM_USERS + item_idx[i - BATCH]);
        acc[(int64_t)i * DIM + lane] += bf2f(x[(int64_t)row * DIM + lane]);
    }
}

// ---------------------------------------------------------------------------
// Output: rating dot + scaled user/item embeddings
// ---------------------------------------------------------------------------
__global__ void out_kernel(const float* __restrict__ acc, float* __restrict__ out) {
    const int lane = threadIdx.x & 63;
    const int b = (int)(((uint32)blockIdx.x * blockDim.x + threadIdx.x) >> 6);
    if (b >= BATCH) return;
    float uv = acc[(int64_t)b * DIM + lane] * 0.25f;
    float iv = acc[(int64_t)(BATCH + b) * DIM + lane] * 0.25f;
    out[(int64_t)BATCH + (int64_t)b * DIM + lane] = uv;
    out[(int64_t)BATCH + (int64_t)BATCH * DIM + (int64_t)b * DIM + lane] = iv;
    float p = uv * iv;
    #pragma unroll
    for (int off = 32; off >= 1; off >>= 1) p += __shfl_down(p, off, 64);
    if (lane == 0) out[b] = p;
}

// ---------------------------------------------------------------------------
extern "C" void kernel_launch(void* const* d_in, const int* in_sizes, int n_in,
                              void* d_out, int out_size, void* d_ws, size_t ws_size,
                              hipStream_t stream) {
    const int*   user_idx = (const int*)  d_in[0];
    const int*   item_idx = (const int*)  d_in[1];
    const int*   rows     = (const int*)  d_in[2];
    const int*   cols     = (const int*)  d_in[3];
    const float* vals     = (const float*)d_in[4];
    const float* user_emb = (const float*)d_in[5];
    const float* item_emb = (const float*)d_in[6];
    float*       out      = (float*)d_out;

    // ---- workspace layout ----
    char* base = (char*)d_ws;
    size_t off = 0;
    auto alloc = [&](size_t bytes) -> char* {
        char* p = base + off;
        off = (off + bytes + 255) & ~(size_t)255;
        return p;
    };
    int*    cnt    = (int*)   alloc((size_t)(N_NODES + 1) * sizeof(int));
    int*    rowptr = (int*)   alloc((size_t)(N_NODES + 1) * sizeof(int));
    int*    cursor = (int*)   alloc((size_t)N_NODES * sizeof(int));
    int*    blksum = (int*)   alloc((size_t)NBLK * sizeof(int));
    int2*   edges  = (int2*)  alloc((size_t)NNZ * sizeof(int2));
    ushort* xb     = (ushort*)alloc((size_t)N_NODES * DIM * sizeof(ushort));
    ushort* buf0   = (ushort*)alloc((size_t)N_NODES * DIM * sizeof(ushort));
    ushort* buf1   = (ushort*)alloc((size_t)N_NODES * DIM * sizeof(ushort));
    float*  acc    = (float*) alloc((size_t)2 * BATCH * DIM * sizeof(float));

    const int TB = 256;

    // ---- CSR build ----
    hipMemsetAsync(cnt, 0, (size_t)(N_NODES + 1) * sizeof(int), stream);
    hist_kernel<<<2048, TB, 0, stream>>>(rows, cnt);
    scan_block_kernel<<<NBLK, SCAN_B, 0, stream>>>(cnt, rowptr, blksum);
    scan_top_kernel<<<1, SCAN_B, 0, stream>>>(blksum);
    scan_fix_kernel<<<(N_NODES + TB - 1) / TB, TB, 0, stream>>>(rowptr, blksum, cursor);
    scatter_kernel<<<2048, TB, 0, stream>>>(rows, cols, vals, cursor, edges);

    // ---- bf16 node features ----
    convert_kernel<<<2048, TB, 0, stream>>>(user_emb, item_emb, xb);

    // ---- propagation ----
    const int spmmBlocks = (N_NODES / 8 * 64 + TB - 1) / TB;   // 8 rows per wave
    const int gathBlocks = (2 * BATCH * 64 + TB - 1) / TB;
    const int batchBlocks = (2 * BATCH / 8 * 64 + TB - 1) / TB;

    gather_acc_kernel<true><<<gathBlocks, TB, 0, stream>>>(
        user_idx, item_idx, nullptr, user_emb, item_emb, acc);

    // layer 1: xb -> buf0 ; acc += l1
    spmm8_kernel<<<spmmBlocks, TB, 0, stream>>>(rowptr, edges, xb, buf0);
    gather_acc_kernel<false><<<gathBlocks, TB, 0, stream>>>(
        user_idx, item_idx, buf0, nullptr, nullptr, acc);

    // layer 2: buf0 -> buf1 ; acc += l2
    spmm8_kernel<<<spmmBlocks, TB, 0, stream>>>(rowptr, edges, buf0, buf1);
    gather_acc_kernel<false><<<gathBlocks, TB, 0, stream>>>(
        user_idx, item_idx, buf1, nullptr, nullptr, acc);

    // layer 3: batch rows only, fused into acc
    spmm_batch_kernel<<<batchBlocks, TB, 0, stream>>>(
        user_idx, item_idx, rowptr, edges, buf1, acc);

    // ---- output ----
    out_kernel<<<(BATCH * 64 + TB - 1) / TB, TB, 0, stream>>>(acc, out);
}